// Round 6
// baseline (680.251 us; speedup 1.0000x reference)
//
#include <hip/hip_runtime.h>
#include <hip/hip_fp16.h>
#include <math.h>

#define N_NODES 100000
#define N_EDGES 1600000
#define HDIM    128
#define NCLS    10
#define NGRAPH  1000
#define GEMM_BLOCKS  ((N_NODES + 127) / 128)   // 782
#define GEMM_HALF    391                       // split point for overlap
// radix-bucket CSR build
#define BSHIFT   9
#define BUCKW    (1 << BSHIFT)                 // 512 nodes / bucket
#define NB       ((N_NODES + BUCKW - 1) >> BSHIFT)   // 196
#define EPB      4096                          // edges per chunk block
#define NCHUNKS  ((N_EDGES + EPB - 1) / EPB)   // 391
#define SWZ_BLOCKS 24                          // 6144 threads / 256
#define GB_BLOCKS  ((N_NODES + 255) / 256)     // 391

typedef _Float16 half8 __attribute__((ext_vector_type(8)));
typedef float    f32x4 __attribute__((ext_vector_type(4)));

static __device__ __forceinline__ float elu1(float x) {
  return x > 0.f ? x : (__expf(x) - 1.f);
}

// async 16B global->LDS (m97 pattern; literal size arg)
static __device__ __forceinline__ void gload_lds16(const void* g, void* l) {
  __builtin_amdgcn_global_load_lds(
      (const __attribute__((address_space(1))) unsigned int*)g,
      (__attribute__((address_space(3))) unsigned int*)l, 16, 0, 0);
}

// ---------- MFMA GEMM: Ch[n,128](fp16) = A[n,128] @ Wswz ----------
// v_mfma_f32_16x16x32_f16; block = 4 waves x 32 rows. Layouts (m89/m120):
// A[m=lane&15][k=quad*8+j], D col=lane&15 row=quad*4+reg.
// PRESCALE epilogue multiplies row r by dinv[r] -> h' = dinv*H (R16).
template <bool AHALF, bool PRESCALE>
__device__ __forceinline__
void gemm_mfma_body(const void* __restrict__ Av, const half8* __restrict__ Wswz,
                    __half* __restrict__ Ch, int nrows, half8* WtF, int bid,
                    const float* __restrict__ dinv) {
  int tid = threadIdx.x;
  int wv = tid >> 6, lane = tid & 63;
  int quad = lane >> 4, l15 = lane & 15;
  int m0 = bid * 128 + wv * 32;
  int r0 = m0 + l15;      if (r0 > nrows - 1) r0 = nrows - 1;  // clamp; stores guarded
  int r1 = m0 + 16 + l15; if (r1 > nrows - 1) r1 = nrows - 1;

  // ---- A prefetch into registers (issues before staging) ----
  half8 ah[2][4];
  float4 af[2][4][2];
  if constexpr (AHALF) {
    const __half* Ah = (const __half*)Av;
#pragma unroll
    for (int k0 = 0; k0 < 4; ++k0) {
      ah[0][k0] = *(const half8*)(Ah + (size_t)r0 * 128 + k0 * 32 + quad * 8);
      ah[1][k0] = *(const half8*)(Ah + (size_t)r1 * 128 + k0 * 32 + quad * 8);
    }
  } else {
    const float* Af = (const float*)Av;
#pragma unroll
    for (int k0 = 0; k0 < 4; ++k0) {
      const float* p0 = Af + (size_t)r0 * 128 + k0 * 32 + quad * 8;
      const float* p1 = Af + (size_t)r1 * 128 + k0 * 32 + quad * 8;
      af[0][k0][0] = *(const float4*)p0; af[0][k0][1] = *(const float4*)(p0 + 4);
      af[1][k0][0] = *(const float4*)p1; af[1][k0][1] = *(const float4*)(p1 + 4);
    }
  }

  // ---- async W staging (32KB, linear lane-consecutive -> gload_lds safe) ----
  for (int i = tid; i < 2048; i += 256) gload_lds16(Wswz + i, WtF + i);
  __syncthreads();   // drains vmcnt (A prefetch + staging) before LDS reads

  f32x4 acc[2][8];
#pragma unroll
  for (int mt = 0; mt < 2; ++mt)
#pragma unroll
    for (int nt = 0; nt < 8; ++nt) acc[mt][nt] = (f32x4){0.f, 0.f, 0.f, 0.f};

#pragma unroll
  for (int k0 = 0; k0 < 4; ++k0) {
    half8 a0, a1;
    if constexpr (AHALF) {
      a0 = ah[0][k0];
      a1 = ah[1][k0];
    } else {
      float4 x0 = af[0][k0][0], y0 = af[0][k0][1];
      float4 x1 = af[1][k0][0], y1 = af[1][k0][1];
      a0[0] = (_Float16)x0.x; a0[1] = (_Float16)x0.y;
      a0[2] = (_Float16)x0.z; a0[3] = (_Float16)x0.w;
      a0[4] = (_Float16)y0.x; a0[5] = (_Float16)y0.y;
      a0[6] = (_Float16)y0.z; a0[7] = (_Float16)y0.w;
      a1[0] = (_Float16)x1.x; a1[1] = (_Float16)x1.y;
      a1[2] = (_Float16)x1.z; a1[3] = (_Float16)x1.w;
      a1[4] = (_Float16)y1.x; a1[5] = (_Float16)y1.y;
      a1[6] = (_Float16)y1.z; a1[7] = (_Float16)y1.w;
    }
#pragma unroll
    for (int nt = 0; nt < 8; ++nt) {
      half8 b = WtF[(k0 * 8 + nt) * 64 + lane];
      acc[0][nt] = __builtin_amdgcn_mfma_f32_16x16x32_f16(a0, b, acc[0][nt], 0, 0, 0);
      acc[1][nt] = __builtin_amdgcn_mfma_f32_16x16x32_f16(a1, b, acc[1][nt], 0, 0, 0);
    }
  }

#pragma unroll
  for (int mt = 0; mt < 2; ++mt) {
    float4 dv4 = make_float4(1.f, 1.f, 1.f, 1.f);
    if constexpr (PRESCALE) {
      int rb = m0 + mt * 16 + quad * 4;   // multiple of 4; whole quad in/out
      if (rb >= N_NODES) rb = 0;          // rows unstored anyway
      dv4 = *(const float4*)&dinv[rb];
    }
    const float* dvp = (const float*)&dv4;
#pragma unroll
    for (int r = 0; r < 4; ++r) {
      int row = m0 + mt * 16 + quad * 4 + r;
      if (row < nrows) {
#pragma unroll
        for (int nt = 0; nt < 8; ++nt) {
          float v = acc[mt][nt][r];
          if constexpr (PRESCALE) v *= dvp[r];
          Ch[(size_t)row * 128 + nt * 16 + l15] = __float2half(v);
        }
      }
    }
  }
}

__global__ __launch_bounds__(256)
void gemm_mfma_h(const __half* __restrict__ A, const half8* __restrict__ Wswz,
                 __half* __restrict__ Ch, int nrows,
                 const float* __restrict__ dinv) {
  __shared__ half8 WtF[2048];  // 32 KB
  gemm_mfma_body<true, true>(A, Wswz, Ch, nrows, WtF, blockIdx.x, dinv);
}

// ---------- scatter body (R17: self-contained; local hist + global cursor)
// Computes its chunk's bucket histogram in LDS (ei re-read is L2-hot),
// stages edges bucket-grouped, then claims per-bucket output ranges via
// atomicAdd on gcur[b] -- no cbc/cpre/scan_chunks needed (within-bucket
// order is already non-deterministic downstream).
__device__ __forceinline__
void scatter_body(const int* __restrict__ ei, const int* __restrict__ bbase,
                  int* __restrict__ gcur, int2* __restrict__ ebuf, int c,
                  int* lb, int* lcur, int* s, int2* stage) {
  int t = threadIdx.x;

  // local histogram of this chunk's dst buckets
  if (t < NB) lb[t] = 0;
  __syncthreads();
#pragma unroll
  for (int k = 0; k < EPB / 256; ++k) {
    int e = c * EPB + k * 256 + t;
    if (e < N_EDGES) atomicAdd(&lb[ei[N_EDGES + e] >> BSHIFT], 1);
  }
  __syncthreads();

  // exclusive scan over NB buckets
  int v = (t < NB) ? lb[t] : 0;
  s[t] = v;
  __syncthreads();
#pragma unroll
  for (int d = 1; d < 256; d <<= 1) {
    int val = (t >= d) ? s[t - d] : 0;
    __syncthreads();
    s[t] += val;
    __syncthreads();
  }
  if (t < NB) {
    int excl = s[t] - v;
    lb[t] = excl;
    lcur[t] = excl;
  }
  if (t == 255) lb[NB] = s[255];  // edges in this chunk
  __syncthreads();

  // scatter into LDS (bucket-grouped)
#pragma unroll
  for (int k = 0; k < EPB / 256; ++k) {
    int e = c * EPB + k * 256 + t;
    if (e < N_EDGES) {
      int src = ei[e];
      int d = ei[N_EDGES + e];
      int p = atomicAdd(&lcur[d >> BSHIFT], 1);
      stage[p] = make_int2(src, d);
    }
  }
  __syncthreads();

  // coalesced flush: wave w handles buckets w, w+4, ...; global cursor
  int wv = t >> 6, lane = t & 63;
  for (int b = wv; b < NB; b += 4) {
    int l0 = lb[b], l1 = lb[b + 1];
    int cnt = l1 - l0;
    if (cnt == 0) continue;
    int pos = 0;
    if (lane == 0) pos = atomicAdd(&gcur[b], cnt);
    pos = __builtin_amdgcn_readfirstlane(pos);
    int gb = bbase[b] + pos;
    for (int i = lane; i < cnt; i += 64) ebuf[gb + i] = stage[l0 + i];
  }
}

// ---------- bucket_csr body (hist + scan -> off/dinv + dst-sorted csrc) ---
__device__ __forceinline__
void csr_body(const int2* __restrict__ ebuf, const int* __restrict__ bbase,
              int* __restrict__ off, float* __restrict__ dinv,
              int* __restrict__ csrc, int b, int* hist, int* cur, int* s) {
  int t = threadIdx.x;
  int node0 = b << BSHIFT;
  int ebeg = bbase[b], eend = bbase[b + 1];

  hist[t] = 0; hist[t + 256] = 0;
  __syncthreads();
  for (int e = ebeg + t; e < eend; e += 256)
    atomicAdd(&hist[ebuf[e].y - node0], 1);
  __syncthreads();

  int a = hist[2 * t], bq = hist[2 * t + 1];
  int sum = a + bq;
  s[t] = sum;
  __syncthreads();
#pragma unroll
  for (int d = 1; d < 256; d <<= 1) {
    int val = (t >= d) ? s[t - d] : 0;
    __syncthreads();
    s[t] += val;
    __syncthreads();
  }
  int run = s[t] - sum;
  cur[2 * t] = run;
  cur[2 * t + 1] = run + a;

  int i0 = node0 + 2 * t, i1 = node0 + 2 * t + 1;
  if (i0 < N_NODES) {
    off[i0] = ebeg + run;
    dinv[i0] = rsqrtf((float)(a + 1));
  }
  if (i1 < N_NODES) {
    off[i1] = ebeg + run + a;
    dinv[i1] = rsqrtf((float)(bq + 1));
  }
  if (b == NB - 1 && t == 0) off[N_NODES] = N_EDGES;
  __syncthreads();

  for (int e = ebeg + t; e < eend; e += 256) {
    int2 ed = ebuf[e];
    int p = atomicAdd(&cur[ed.y - node0], 1);
    csrc[ebeg + p] = ed.x;
  }
}

// ---------- MERGED front-end: swizzle_w || bucket_count(->btot) || gbound -
__global__ __launch_bounds__(256)
void front1(const float* __restrict__ W0, const float* __restrict__ W1,
            const float* __restrict__ W2, half8* __restrict__ Wswz,
            const int* __restrict__ ei, int* __restrict__ btot,
            const int* __restrict__ batch, int* __restrict__ goff) {
  int bid = blockIdx.x;
  int t = threadIdx.x;
  if (bid < SWZ_BLOCKS) {
    // ---- W swizzle: f32 [128][128] -> fp16 B-fragment order (m89) ----
    int f = bid * 256 + t;            // 0..6143
    int which = f >> 11;
    const float* W = (which == 0) ? W0 : ((which == 1) ? W1 : W2);
    int r = f & 2047;
    int frag = r >> 6;                // k0*8+nt
    int lane = r & 63;
    int k0 = frag >> 3, nt = frag & 7;
    int n = nt * 16 + (lane & 15);
    int kbase = k0 * 32 + (lane >> 4) * 8;
    half8 hb;
#pragma unroll
    for (int j = 0; j < 8; ++j) hb[j] = (_Float16)W[(kbase + j) * 128 + n];
    Wswz[f] = hb;
  } else if (bid < SWZ_BLOCKS + NCHUNKS) {
    // ---- per-chunk histogram -> global bucket totals (atomic) ----
    __shared__ int hist[NB];
    int c = bid - SWZ_BLOCKS;
    if (t < NB) hist[t] = 0;
    __syncthreads();
#pragma unroll
    for (int k = 0; k < EPB / 256; ++k) {
      int e = c * EPB + k * 256 + t;
      if (e < N_EDGES) atomicAdd(&hist[ei[N_EDGES + e] >> BSHIFT], 1);
    }
    __syncthreads();
    if (t < NB && hist[t] > 0) atomicAdd(&btot[t], hist[t]);
  } else {
    // ---- graph (pooling) ranges from SORTED batch ----
    int i = (bid - SWZ_BLOCKS - NCHUNKS) * 256 + t;
    if (i >= N_NODES) return;
    int b = batch[i];
    if (i == 0) {
      for (int g = 0; g <= b; ++g) goff[g] = 0;
    } else {
      int a = batch[i - 1];
      for (int g = a + 1; g <= b; ++g) goff[g] = i;
    }
    if (i == N_NODES - 1) {
      for (int g = b + 1; g <= NGRAPH; ++g) goff[g] = N_NODES;
    }
  }
}

// B2: exclusive scan over bucket totals -> bbase[b], bbase[NB] = E
__global__ __launch_bounds__(256)
void scan_base(const int* __restrict__ btot, int* __restrict__ bbase) {
  __shared__ int s[256];
  int t = threadIdx.x;
  int v = (t < NB) ? btot[t] : 0;
  s[t] = v;
  __syncthreads();
#pragma unroll
  for (int d = 1; d < 256; d <<= 1) {
    int val = (t >= d) ? s[t - d] : 0;
    __syncthreads();
    s[t] += val;
    __syncthreads();
  }
  if (t < NB) bbase[t] = s[t] - v;
  if (t == 255) bbase[NB] = s[255];  // == N_EDGES
}

// ---------- midA: scatter(391) || gemm0 tiles 0..390 ----------------------
__global__ __launch_bounds__(256)
void midA(const float* __restrict__ x, const half8* __restrict__ Wswz,
          __half* __restrict__ hbuf,
          const int* __restrict__ ei, const int* __restrict__ bbase,
          int* __restrict__ gcur, int2* __restrict__ ebuf) {
  __shared__ union {
    half8 WtF[2048];                                    // 32 KB (gemm path)
    struct { int lb[NB + 1]; int lcur[NB]; int s[256]; int2 stage[EPB]; } sc;
  } u;
  int bid = blockIdx.x;
  if (bid < NCHUNKS) {
    scatter_body(ei, bbase, gcur, ebuf, bid,
                 u.sc.lb, u.sc.lcur, u.sc.s, u.sc.stage);
  } else {
    gemm_mfma_body<false, false>(x, Wswz, hbuf, N_NODES, u.WtF,
                                 bid - NCHUNKS, nullptr);
  }
}

// ---------- midB: csr(196) || gemm0 tiles 391..781 ------------------------
// R17: csr alone is 0.76 blocks/CU latency-bound; fill idle CUs with the
// second half of gemm0's tiles.
__global__ __launch_bounds__(256)
void midB(const float* __restrict__ x, const half8* __restrict__ Wswz,
          __half* __restrict__ hbuf,
          const int2* __restrict__ ebuf, const int* __restrict__ bbase,
          int* __restrict__ off, float* __restrict__ dinv,
          int* __restrict__ csrc) {
  __shared__ union {
    half8 WtF[2048];                                    // 32 KB (gemm path)
    struct { int hist[BUCKW]; int cur[BUCKW]; int s[256]; } cs;  // 5.1 KB
  } u;
  int bid = blockIdx.x;
  if (bid < NB) {
    csr_body(ebuf, bbase, off, dinv, csrc, bid, u.cs.hist, u.cs.cur, u.cs.s);
  } else {
    gemm_mfma_body<false, false>(x, Wswz, hbuf, N_NODES, u.WtF,
                                 (bid - NB) + GEMM_HALF, nullptr);
  }
}

// ---------- aggregation (R1's proven wave/node scalar-path shape) ---------
// PRE consumes prescaled h' = dinv*H: inner loop is csrc -> h2 -> add.
template <bool PRE>
__global__ __launch_bounds__(256)
void aggregate(const __half* __restrict__ h, const int* __restrict__ off,
               const int* __restrict__ csrc, const float* __restrict__ dinv,
               const float* __restrict__ bias, __half* __restrict__ out) {
  int gid = blockIdx.x * blockDim.x + threadIdx.x;
  int node = __builtin_amdgcn_readfirstlane(gid >> 6);   // wave-uniform
  int lane = threadIdx.x & 63;
  if (node >= N_NODES) return;
  const __half2* h2 = (const __half2*)h;

  int beg = off[node], end = off[node + 1];
  float a0 = 0.f, a1 = 0.f;
  float b0_ = 0.f, b1_ = 0.f;
  float c0 = 0.f, c1 = 0.f;
  float d0 = 0.f, d1 = 0.f;

  int e = beg;
  for (; e + 8 <= end; e += 8) {
    int s0 = csrc[e + 0], s1 = csrc[e + 1], s2 = csrc[e + 2], s3 = csrc[e + 3];
    int s4 = csrc[e + 4], s5 = csrc[e + 5], s6 = csrc[e + 6], s7 = csrc[e + 7];
    float2 f0 = __half22float2(h2[(size_t)s0 * 64 + lane]);
    float2 f1 = __half22float2(h2[(size_t)s1 * 64 + lane]);
    float2 f2 = __half22float2(h2[(size_t)s2 * 64 + lane]);
    float2 f3 = __half22float2(h2[(size_t)s3 * 64 + lane]);
    float2 f4 = __half22float2(h2[(size_t)s4 * 64 + lane]);
    float2 f5 = __half22float2(h2[(size_t)s5 * 64 + lane]);
    float2 f6 = __half22float2(h2[(size_t)s6 * 64 + lane]);
    float2 f7 = __half22float2(h2[(size_t)s7 * 64 + lane]);
    if constexpr (PRE) {
      a0 += f0.x; a1 += f0.y;  b0_ += f1.x; b1_ += f1.y;
      c0 += f2.x; c1 += f2.y;  d0 += f3.x; d1 += f3.y;
      a0 += f4.x; a1 += f4.y;  b0_ += f5.x; b1_ += f5.y;
      c0 += f6.x; c1 += f6.y;  d0 += f7.x; d1 += f7.y;
    } else {
      float w0 = dinv[s0], w1 = dinv[s1], w2 = dinv[s2], w3 = dinv[s3];
      float w4 = dinv[s4], w5 = dinv[s5], w6 = dinv[s6], w7 = dinv[s7];
      a0 = fmaf(w0, f0.x, a0); a1 = fmaf(w0, f0.y, a1);
      b0_ = fmaf(w1, f1.x, b0_); b1_ = fmaf(w1, f1.y, b1_);
      c0 = fmaf(w2, f2.x, c0); c1 = fmaf(w2, f2.y, c1);
      d0 = fmaf(w3, f3.x, d0); d1 = fmaf(w3, f3.y, d1);
      a0 = fmaf(w4, f4.x, a0); a1 = fmaf(w4, f4.y, a1);
      b0_ = fmaf(w5, f5.x, b0_); b1_ = fmaf(w5, f5.y, b1_);
      c0 = fmaf(w6, f6.x, c0); c1 = fmaf(w6, f6.y, c1);
      d0 = fmaf(w7, f7.x, d0); d1 = fmaf(w7, f7.y, d1);
    }
  }
  if (e + 4 <= end) {
    int s0 = csrc[e + 0], s1 = csrc[e + 1], s2 = csrc[e + 2], s3 = csrc[e + 3];
    float2 f0 = __half22float2(h2[(size_t)s0 * 64 + lane]);
    float2 f1 = __half22float2(h2[(size_t)s1 * 64 + lane]);
    float2 f2 = __half22float2(h2[(size_t)s2 * 64 + lane]);
    float2 f3 = __half22float2(h2[(size_t)s3 * 64 + lane]);
    if constexpr (PRE) {
      a0 += f0.x; a1 += f0.y;  b0_ += f1.x; b1_ += f1.y;
      c0 += f2.x; c1 += f2.y;  d0 += f3.x; d1 += f3.y;
    } else {
      float w0 = dinv[s0], w1 = dinv[s1], w2 = dinv[s2], w3 = dinv[s3];
      a0 = fmaf(w0, f0.x, a0); a1 = fmaf(w0, f0.y, a1);
      b0_ = fmaf(w1, f1.x, b0_); b1_ = fmaf(w1, f1.y, b1_);
      c0 = fmaf(w2, f2.x, c0); c1 = fmaf(w2, f2.y, c1);
      d0 = fmaf(w3, f3.x, d0); d1 = fmaf(w3, f3.y, d1);
    }
    e += 4;
  }
  if (e + 2 <= end) {
    int s0 = csrc[e + 0], s1 = csrc[e + 1];
    float2 f0 = __half22float2(h2[(size_t)s0 * 64 + lane]);
    float2 f1 = __half22float2(h2[(size_t)s1 * 64 + lane]);
    if constexpr (PRE) {
      a0 += f0.x; a1 += f0.y;  b0_ += f1.x; b1_ += f1.y;
    } else {
      float w0 = dinv[s0], w1 = dinv[s1];
      a0 = fmaf(w0, f0.x, a0); a1 = fmaf(w0, f0.y, a1);
      b0_ = fmaf(w1, f1.x, b0_); b1_ = fmaf(w1, f1.y, b1_);
    }
    e += 2;
  }
  if (e < end) {
    int s0 = csrc[e];
    float2 f0 = __half22float2(h2[(size_t)s0 * 64 + lane]);
    if constexpr (PRE) {
      a0 += f0.x; a1 += f0.y;
    } else {
      float w0 = dinv[s0];
      a0 = fmaf(w0, f0.x, a0); a1 = fmaf(w0, f0.y, a1);
    }
  }

  float dv = dinv[node];
  float2 vs = __half22float2(h2[(size_t)node * 64 + lane]);
  float s0f, s1f;
  if constexpr (PRE) {
    // vs is already h' = dinv*H; self term dinv^2*H = dinv*h'
    s0f = ((a0 + b0_) + (c0 + d0) + vs.x) * dv;
    s1f = ((a1 + b1_) + (c1 + d1) + vs.y) * dv;
  } else {
    s0f = ((a0 + b0_) + (c0 + d0) + dv * vs.x) * dv;
    s1f = ((a1 + b1_) + (c1 + d1) + dv * vs.y) * dv;
  }

  float2 bb = ((const float2*)bias)[lane];
  float ox = elu1(s0f + bb.x);
  float oy = elu1(s1f + bb.y);
  ((__half2*)out)[(size_t)node * 64 + lane] = __floats2half2_rn(ox, oy);
}

// ---------- fused max-pool + linear head + softmax ----------
__global__ __launch_bounds__(256)
void pool_head(const __half* __restrict__ feat, const int* __restrict__ goff,
               const float* __restrict__ Wl, const float* __restrict__ bl,
               float* __restrict__ out) {
  int g = blockIdx.x;
  int t = threadIdx.x;          // 0..255
  int fp = t & 63;              // feature pair (2fp, 2fp+1)
  int r = t >> 6;               // row stream 0..3
  int beg = goff[g], end = goff[g + 1];
  const __half2* f2 = (const __half2*)feat;   // row stride 64

  float m0x = -INFINITY, m0y = -INFINITY, m1x = -INFINITY, m1y = -INFINITY;
  int i = beg + r;
  for (; i + 4 < end; i += 8) {
    float2 u = __half22float2(f2[(size_t)i * 64 + fp]);
    float2 v = __half22float2(f2[(size_t)(i + 4) * 64 + fp]);
    m0x = fmaxf(m0x, u.x); m0y = fmaxf(m0y, u.y);
    m1x = fmaxf(m1x, v.x); m1y = fmaxf(m1y, v.y);
  }
  for (; i < end; i += 4) {
    float2 u = __half22float2(f2[(size_t)i * 64 + fp]);
    m0x = fmaxf(m0x, u.x); m0y = fmaxf(m0y, u.y);
  }
  m0x = fmaxf(m0x, m1x); m0y = fmaxf(m0y, m1y);

  __shared__ float pl[4][HDIM];
  __shared__ float red[HDIM];
  __shared__ float lg[NCLS];
  pl[r][2 * fp] = m0x;
  pl[r][2 * fp + 1] = m0y;
  __syncthreads();

  if (t < HDIM) {
    float mm = fmaxf(fmaxf(pl[0][t], pl[1][t]), fmaxf(pl[2][t], pl[3][t]));
    if (beg == end) mm = 0.f;
    red[t] = mm;
  }
  __syncthreads();

  if (t < NCLS) {
    float acc = bl[t];
#pragma unroll
    for (int ff = 0; ff < HDIM; ++ff) acc = fmaf(red[ff], Wl[ff * NCLS + t], acc);
    lg[t] = acc;
  }
  __syncthreads();

  if (t < NCLS) {
    float mx = lg[0];
#pragma unroll
    for (int c = 1; c < NCLS; ++c) mx = fmaxf(mx, lg[c]);
    float ssum = 0.f;
#pragma unroll
    for (int c = 0; c < NCLS; ++c) ssum += __expf(lg[c] - mx);
    out[g * NCLS + t] = __expf(lg[t] - mx) / ssum;
  }
}

// ---------- launch ----------

extern "C" void kernel_launch(void* const* d_in, const int* in_sizes, int n_in,
                              void* d_out, int out_size, void* d_ws, size_t ws_size,
                              hipStream_t stream) {
  const float* x    = (const float*)d_in[0];
  const int*   ei   = (const int*)d_in[1];
  const int*   batch= (const int*)d_in[2];
  const float* W0 = (const float*)d_in[3]; const float* b0 = (const float*)d_in[4];
  const float* W1 = (const float*)d_in[5]; const float* b1 = (const float*)d_in[6];
  const float* W2 = (const float*)d_in[7]; const float* b2 = (const float*)d_in[8];
  const float* Wl = (const float*)d_in[9]; const float* bl = (const float*)d_in[10];
  float* out = (float*)d_out;

  char* w = (char*)d_ws;
  auto alloc = [&](size_t bytes) {
    char* p = w;
    w += (bytes + 255) & ~(size_t)255;
    return p;
  };
  // btot and gcur in one zeroed buffer (single memset)
  int*    zbuf   = (int*)   alloc((size_t)2 * NB * 4);
  int*    btot   = zbuf;
  int*    gcur   = zbuf + NB;
  int*    bbase  = (int*)   alloc((size_t)(NB + 1) * 4);
  int2*   ebuf   = (int2*)  alloc((size_t)N_EDGES * 8);
  int*    off    = (int*)   alloc((size_t)(N_NODES + 1) * 4);
  float*  dinv   = (float*) alloc((size_t)N_NODES * 4);
  int*    goff   = (int*)   alloc((size_t)(NGRAPH + 1) * 4);
  int*    csrc   = (int*)   alloc((size_t)N_EDGES * 4);
  half8*  Wswz   = (half8*) alloc((size_t)3 * 2048 * 16);
  __half* hbufA  = (__half*)alloc((size_t)N_NODES * HDIM * 2);
  __half* feat   = (__half*)alloc((size_t)N_NODES * HDIM * 2);

  hipMemsetAsync(zbuf, 0, (size_t)2 * NB * 4, stream);

  // merged front-end: W swizzle || bucket totals (global atomic) || gbound
  front1<<<SWZ_BLOCKS + NCHUNKS + GB_BLOCKS, 256, 0, stream>>>(
      W0, W1, W2, Wswz, ei, btot, batch, goff);

  scan_base<<<1, 256, 0, stream>>>(btot, bbase);

  // scatter || gemm0 first half
  midA<<<NCHUNKS + GEMM_HALF, 256, 0, stream>>>(
      x, Wswz, hbufA, ei, bbase, gcur, ebuf);

  // csr finalize || gemm0 second half
  midB<<<NB + (GEMM_BLOCKS - GEMM_HALF), 256, 0, stream>>>(
      x, Wswz, hbufA, ebuf, bbase, off, dinv, csrc);

  const int AGG_BLOCKS = ((size_t)N_NODES * 64 + 255) / 256;   // 25000

  // layer 1: NONPRE (gemm0 ran before dinv existed)
  aggregate<false><<<AGG_BLOCKS, 256, 0, stream>>>(
      hbufA, off, csrc, dinv, b0, feat);

  // layers 2,3: GEMM epilogue prescales -> PRE aggregate (no dinv chain)
  gemm_mfma_h<<<GEMM_BLOCKS, 256, 0, stream>>>(feat, Wswz + 2048, hbufA,
                                               N_NODES, dinv);
  aggregate<true><<<AGG_BLOCKS, 256, 0, stream>>>(
      hbufA, off, csrc, dinv, b1, feat);

  gemm_mfma_h<<<GEMM_BLOCKS, 256, 0, stream>>>(feat, Wswz + 4096, hbufA,
                                               N_NODES, dinv);
  aggregate<true><<<AGG_BLOCKS, 256, 0, stream>>>(
      hbufA, off, csrc, dinv, b2, feat);

  pool_head<<<NGRAPH, 256, 0, stream>>>(feat, goff, Wl, bl, out);
}

// Round 7
// 379.260 us; speedup vs baseline: 1.7936x; 1.7936x over previous
//
#include <hip/hip_runtime.h>
#include <hip/hip_fp16.h>
#include <math.h>

#define N_NODES 100000
#define N_EDGES 1600000
#define HDIM    128
#define NCLS    10
#define NGRAPH  1000
#define GEMM_BLOCKS  ((N_NODES + 127) / 128)   // 782
#define GEMM_HALF    391                       // split point for overlap
// radix-bucket CSR build
#define BSHIFT   9
#define BUCKW    (1 << BSHIFT)                 // 512 nodes / bucket
#define NB       ((N_NODES + BUCKW - 1) >> BSHIFT)   // 196
#define EPB      4096                          // edges per chunk block
#define NCHUNKS  ((N_EDGES + EPB - 1) / EPB)   // 391
#define SWZ_BLOCKS 24                          // 6144 threads / 256
#define GB_BLOCKS  ((N_NODES + 255) / 256)     // 391

typedef _Float16 half8 __attribute__((ext_vector_type(8)));
typedef float    f32x4 __attribute__((ext_vector_type(4)));

static __device__ __forceinline__ float elu1(float x) {
  return x > 0.f ? x : (__expf(x) - 1.f);
}

// async 16B global->LDS (m97 pattern; literal size arg)
static __device__ __forceinline__ void gload_lds16(const void* g, void* l) {
  __builtin_amdgcn_global_load_lds(
      (const __attribute__((address_space(1))) unsigned int*)g,
      (__attribute__((address_space(3))) unsigned int*)l, 16, 0, 0);
}

// ---------- MFMA GEMM: Ch[n,128](fp16) = A[n,128] @ Wswz ----------
// v_mfma_f32_16x16x32_f16; block = 4 waves x 32 rows. Layouts (m89/m120):
// A[m=lane&15][k=quad*8+j], D col=lane&15 row=quad*4+reg.
// PRESCALE epilogue multiplies row r by dinv[r] -> h' = dinv*H (R16).
template <bool AHALF, bool PRESCALE>
__device__ __forceinline__
void gemm_mfma_body(const void* __restrict__ Av, const half8* __restrict__ Wswz,
                    __half* __restrict__ Ch, int nrows, half8* WtF, int bid,
                    const float* __restrict__ dinv) {
  int tid = threadIdx.x;
  int wv = tid >> 6, lane = tid & 63;
  int quad = lane >> 4, l15 = lane & 15;
  int m0 = bid * 128 + wv * 32;
  int r0 = m0 + l15;      if (r0 > nrows - 1) r0 = nrows - 1;  // clamp; stores guarded
  int r1 = m0 + 16 + l15; if (r1 > nrows - 1) r1 = nrows - 1;

  // ---- A prefetch into registers (issues before staging) ----
  half8 ah[2][4];
  float4 af[2][4][2];
  if constexpr (AHALF) {
    const __half* Ah = (const __half*)Av;
#pragma unroll
    for (int k0 = 0; k0 < 4; ++k0) {
      ah[0][k0] = *(const half8*)(Ah + (size_t)r0 * 128 + k0 * 32 + quad * 8);
      ah[1][k0] = *(const half8*)(Ah + (size_t)r1 * 128 + k0 * 32 + quad * 8);
    }
  } else {
    const float* Af = (const float*)Av;
#pragma unroll
    for (int k0 = 0; k0 < 4; ++k0) {
      const float* p0 = Af + (size_t)r0 * 128 + k0 * 32 + quad * 8;
      const float* p1 = Af + (size_t)r1 * 128 + k0 * 32 + quad * 8;
      af[0][k0][0] = *(const float4*)p0; af[0][k0][1] = *(const float4*)(p0 + 4);
      af[1][k0][0] = *(const float4*)p1; af[1][k0][1] = *(const float4*)(p1 + 4);
    }
  }

  // ---- async W staging (32KB, linear lane-consecutive -> gload_lds safe) ----
  for (int i = tid; i < 2048; i += 256) gload_lds16(Wswz + i, WtF + i);
  __syncthreads();   // drains vmcnt (A prefetch + staging) before LDS reads

  f32x4 acc[2][8];
#pragma unroll
  for (int mt = 0; mt < 2; ++mt)
#pragma unroll
    for (int nt = 0; nt < 8; ++nt) acc[mt][nt] = (f32x4){0.f, 0.f, 0.f, 0.f};

#pragma unroll
  for (int k0 = 0; k0 < 4; ++k0) {
    half8 a0, a1;
    if constexpr (AHALF) {
      a0 = ah[0][k0];
      a1 = ah[1][k0];
    } else {
      float4 x0 = af[0][k0][0], y0 = af[0][k0][1];
      float4 x1 = af[1][k0][0], y1 = af[1][k0][1];
      a0[0] = (_Float16)x0.x; a0[1] = (_Float16)x0.y;
      a0[2] = (_Float16)x0.z; a0[3] = (_Float16)x0.w;
      a0[4] = (_Float16)y0.x; a0[5] = (_Float16)y0.y;
      a0[6] = (_Float16)y0.z; a0[7] = (_Float16)y0.w;
      a1[0] = (_Float16)x1.x; a1[1] = (_Float16)x1.y;
      a1[2] = (_Float16)x1.z; a1[3] = (_Float16)x1.w;
      a1[4] = (_Float16)y1.x; a1[5] = (_Float16)y1.y;
      a1[6] = (_Float16)y1.z; a1[7] = (_Float16)y1.w;
    }
#pragma unroll
    for (int nt = 0; nt < 8; ++nt) {
      half8 b = WtF[(k0 * 8 + nt) * 64 + lane];
      acc[0][nt] = __builtin_amdgcn_mfma_f32_16x16x32_f16(a0, b, acc[0][nt], 0, 0, 0);
      acc[1][nt] = __builtin_amdgcn_mfma_f32_16x16x32_f16(a1, b, acc[1][nt], 0, 0, 0);
    }
  }

#pragma unroll
  for (int mt = 0; mt < 2; ++mt) {
    float4 dv4 = make_float4(1.f, 1.f, 1.f, 1.f);
    if constexpr (PRESCALE) {
      int rb = m0 + mt * 16 + quad * 4;   // multiple of 4; whole quad in/out
      if (rb >= N_NODES) rb = 0;          // rows unstored anyway
      dv4 = *(const float4*)&dinv[rb];
    }
    const float* dvp = (const float*)&dv4;
#pragma unroll
    for (int r = 0; r < 4; ++r) {
      int row = m0 + mt * 16 + quad * 4 + r;
      if (row < nrows) {
#pragma unroll
        for (int nt = 0; nt < 8; ++nt) {
          float v = acc[mt][nt][r];
          if constexpr (PRESCALE) v *= dvp[r];
          Ch[(size_t)row * 128 + nt * 16 + l15] = __float2half(v);
        }
      }
    }
  }
}

__global__ __launch_bounds__(256)
void gemm_mfma_h(const __half* __restrict__ A, const half8* __restrict__ Wswz,
                 __half* __restrict__ Ch, int nrows,
                 const float* __restrict__ dinv) {
  __shared__ half8 WtF[2048];  // 32 KB
  gemm_mfma_body<true, true>(A, Wswz, Ch, nrows, WtF, blockIdx.x, dinv);
}

// ---------- scatter body (R5's proven form: precomputed cpre offsets) -----
// R18 note: R6's global-cursor variant was a 380us convoy of contended
// device atomics (49 serialized round-trips/wave x 1564 waves on 6 cache
// lines). Deterministic cpre offsets keep the flush dependency-free.
__device__ __forceinline__
void scatter_body(const int* __restrict__ ei, const int* __restrict__ cbc,
                  const int* __restrict__ cpre, const int* __restrict__ bbase,
                  int2* __restrict__ ebuf, int c,
                  int* lb, int* lcur, int* s, int2* stage) {
  int t = threadIdx.x;

  // local exclusive scan of this chunk's bucket counts
  int v = (t < NB) ? cbc[c * NB + t] : 0;
  s[t] = v;
  __syncthreads();
#pragma unroll
  for (int d = 1; d < 256; d <<= 1) {
    int val = (t >= d) ? s[t - d] : 0;
    __syncthreads();
    s[t] += val;
    __syncthreads();
  }
  if (t < NB) {
    int excl = s[t] - v;
    lb[t] = excl;
    lcur[t] = excl;
  }
  if (t == 255) lb[NB] = s[255];  // edges in this chunk
  __syncthreads();

  // scatter into LDS (bucket-grouped)
#pragma unroll
  for (int k = 0; k < EPB / 256; ++k) {
    int e = c * EPB + k * 256 + t;
    if (e < N_EDGES) {
      int src = ei[e];
      int d = ei[N_EDGES + e];
      int p = atomicAdd(&lcur[d >> BSHIFT], 1);
      stage[p] = make_int2(src, d);
    }
  }
  __syncthreads();

  // coalesced flush: wave w handles buckets w, w+4, ...
  int wv = t >> 6, lane = t & 63;
  for (int b = wv; b < NB; b += 4) {
    int l0 = lb[b], l1 = lb[b + 1];
    int gb = bbase[b] + cpre[c * NB + b];
    for (int i = lane; i < l1 - l0; i += 64) ebuf[gb + i] = stage[l0 + i];
  }
}

// ---------- bucket_csr body (hist + scan -> off/dinv + dst-sorted csrc) ---
__device__ __forceinline__
void csr_body(const int2* __restrict__ ebuf, const int* __restrict__ bbase,
              int* __restrict__ off, float* __restrict__ dinv,
              int* __restrict__ csrc, int b, int* hist, int* cur, int* s) {
  int t = threadIdx.x;
  int node0 = b << BSHIFT;
  int ebeg = bbase[b], eend = bbase[b + 1];

  hist[t] = 0; hist[t + 256] = 0;
  __syncthreads();
  for (int e = ebeg + t; e < eend; e += 256)
    atomicAdd(&hist[ebuf[e].y - node0], 1);
  __syncthreads();

  int a = hist[2 * t], bq = hist[2 * t + 1];
  int sum = a + bq;
  s[t] = sum;
  __syncthreads();
#pragma unroll
  for (int d = 1; d < 256; d <<= 1) {
    int val = (t >= d) ? s[t - d] : 0;
    __syncthreads();
    s[t] += val;
    __syncthreads();
  }
  int run = s[t] - sum;
  cur[2 * t] = run;
  cur[2 * t + 1] = run + a;

  int i0 = node0 + 2 * t, i1 = node0 + 2 * t + 1;
  if (i0 < N_NODES) {
    off[i0] = ebeg + run;
    dinv[i0] = rsqrtf((float)(a + 1));
  }
  if (i1 < N_NODES) {
    off[i1] = ebeg + run + a;
    dinv[i1] = rsqrtf((float)(bq + 1));
  }
  if (b == NB - 1 && t == 0) off[N_NODES] = N_EDGES;
  __syncthreads();

  for (int e = ebeg + t; e < eend; e += 256) {
    int2 ed = ebuf[e];
    int p = atomicAdd(&cur[ed.y - node0], 1);
    csrc[ebeg + p] = ed.x;
  }
}

// ---------- MERGED front-end: swizzle_w || bucket_count || gbound ---------
__global__ __launch_bounds__(256)
void front1(const float* __restrict__ W0, const float* __restrict__ W1,
            const float* __restrict__ W2, half8* __restrict__ Wswz,
            const int* __restrict__ ei, int* __restrict__ cbc,
            const int* __restrict__ batch, int* __restrict__ goff) {
  int bid = blockIdx.x;
  int t = threadIdx.x;
  if (bid < SWZ_BLOCKS) {
    // ---- W swizzle: f32 [128][128] -> fp16 B-fragment order (m89) ----
    int f = bid * 256 + t;            // 0..6143
    int which = f >> 11;
    const float* W = (which == 0) ? W0 : ((which == 1) ? W1 : W2);
    int r = f & 2047;
    int frag = r >> 6;                // k0*8+nt
    int lane = r & 63;
    int k0 = frag >> 3, nt = frag & 7;
    int n = nt * 16 + (lane & 15);
    int kbase = k0 * 32 + (lane >> 4) * 8;
    half8 hb;
#pragma unroll
    for (int j = 0; j < 8; ++j) hb[j] = (_Float16)W[(kbase + j) * 128 + n];
    Wswz[f] = hb;
  } else if (bid < SWZ_BLOCKS + NCHUNKS) {
    // ---- per-chunk histogram over 196 buckets ----
    __shared__ int hist[NB];
    int c = bid - SWZ_BLOCKS;
    if (t < NB) hist[t] = 0;
    __syncthreads();
#pragma unroll
    for (int k = 0; k < EPB / 256; ++k) {
      int e = c * EPB + k * 256 + t;
      if (e < N_EDGES) atomicAdd(&hist[ei[N_EDGES + e] >> BSHIFT], 1);
    }
    __syncthreads();
    if (t < NB) cbc[c * NB + t] = hist[t];
  } else {
    // ---- graph (pooling) ranges from SORTED batch ----
    int i = (bid - SWZ_BLOCKS - NCHUNKS) * 256 + t;
    if (i >= N_NODES) return;
    int b = batch[i];
    if (i == 0) {
      for (int g = 0; g <= b; ++g) goff[g] = 0;
    } else {
      int a = batch[i - 1];
      for (int g = a + 1; g <= b; ++g) goff[g] = i;
    }
    if (i == N_NODES - 1) {
      for (int g = b + 1; g <= NGRAPH; ++g) goff[g] = N_NODES;
    }
  }
}

// B1: per-bucket exclusive scan along the chunk axis (parallel over buckets)
__global__ __launch_bounds__(256)
void scan_chunks(const int* __restrict__ cbc, int* __restrict__ cpre,
                 int* __restrict__ btot) {
  __shared__ int s[256];
  int b = blockIdx.x;
  int t = threadIdx.x;
  int c0 = 2 * t, c1 = 2 * t + 1;
  int v0 = (c0 < NCHUNKS) ? cbc[c0 * NB + b] : 0;
  int v1 = (c1 < NCHUNKS) ? cbc[c1 * NB + b] : 0;
  int sum = v0 + v1;
  s[t] = sum;
  __syncthreads();
#pragma unroll
  for (int d = 1; d < 256; d <<= 1) {
    int val = (t >= d) ? s[t - d] : 0;
    __syncthreads();
    s[t] += val;
    __syncthreads();
  }
  int run = s[t] - sum;
  if (c0 < NCHUNKS) cpre[c0 * NB + b] = run;
  if (c1 < NCHUNKS) cpre[c1 * NB + b] = run + v0;
  if (t == 255) btot[b] = s[255];
}

// B2: exclusive scan over bucket totals -> bbase[b], bbase[NB] = E
__global__ __launch_bounds__(256)
void scan_base(const int* __restrict__ btot, int* __restrict__ bbase) {
  __shared__ int s[256];
  int t = threadIdx.x;
  int v = (t < NB) ? btot[t] : 0;
  s[t] = v;
  __syncthreads();
#pragma unroll
  for (int d = 1; d < 256; d <<= 1) {
    int val = (t >= d) ? s[t - d] : 0;
    __syncthreads();
    s[t] += val;
    __syncthreads();
  }
  if (t < NB) bbase[t] = s[t] - v;
  if (t == 255) bbase[NB] = s[255];  // == N_EDGES
}

// ---------- midA: scatter(391) || gemm0 tiles 0..390 ----------------------
__global__ __launch_bounds__(256)
void midA(const float* __restrict__ x, const half8* __restrict__ Wswz,
          __half* __restrict__ hbuf,
          const int* __restrict__ ei, const int* __restrict__ cbc,
          const int* __restrict__ cpre, const int* __restrict__ bbase,
          int2* __restrict__ ebuf) {
  __shared__ union {
    half8 WtF[2048];                                    // 32 KB (gemm path)
    struct { int lb[NB + 1]; int lcur[NB]; int s[256]; int2 stage[EPB]; } sc;
  } u;
  int bid = blockIdx.x;
  if (bid < NCHUNKS) {
    scatter_body(ei, cbc, cpre, bbase, ebuf, bid,
                 u.sc.lb, u.sc.lcur, u.sc.s, u.sc.stage);
  } else {
    gemm_mfma_body<false, false>(x, Wswz, hbuf, N_NODES, u.WtF,
                                 bid - NCHUNKS, nullptr);
  }
}

// ---------- midB: csr(196) || gemm0 tiles 391..781 ------------------------
// R18: csr alone is 0.76 blocks/CU latency-bound; fill idle CUs with the
// second half of gemm0's tiles.
__global__ __launch_bounds__(256)
void midB(const float* __restrict__ x, const half8* __restrict__ Wswz,
          __half* __restrict__ hbuf,
          const int2* __restrict__ ebuf, const int* __restrict__ bbase,
          int* __restrict__ off, float* __restrict__ dinv,
          int* __restrict__ csrc) {
  __shared__ union {
    half8 WtF[2048];                                    // 32 KB (gemm path)
    struct { int hist[BUCKW]; int cur[BUCKW]; int s[256]; } cs;  // 5.1 KB
  } u;
  int bid = blockIdx.x;
  if (bid < NB) {
    csr_body(ebuf, bbase, off, dinv, csrc, bid, u.cs.hist, u.cs.cur, u.cs.s);
  } else {
    gemm_mfma_body<false, false>(x, Wswz, hbuf, N_NODES, u.WtF,
                                 (bid - NB) + GEMM_HALF, nullptr);
  }
}

// ---------- aggregation (R1's proven wave/node scalar-path shape) ---------
// PRE consumes prescaled h' = dinv*H: inner loop is csrc -> h2 -> add.
template <bool PRE>
__global__ __launch_bounds__(256)
void aggregate(const __half* __restrict__ h, const int* __restrict__ off,
               const int* __restrict__ csrc, const float* __restrict__ dinv,
               const float* __restrict__ bias, __half* __restrict__ out) {
  int gid = blockIdx.x * blockDim.x + threadIdx.x;
  int node = __builtin_amdgcn_readfirstlane(gid >> 6);   // wave-uniform
  int lane = threadIdx.x & 63;
  if (node >= N_NODES) return;
  const __half2* h2 = (const __half2*)h;

  int beg = off[node], end = off[node + 1];
  float a0 = 0.f, a1 = 0.f;
  float b0_ = 0.f, b1_ = 0.f;
  float c0 = 0.f, c1 = 0.f;
  float d0 = 0.f, d1 = 0.f;

  int e = beg;
  for (; e + 8 <= end; e += 8) {
    int s0 = csrc[e + 0], s1 = csrc[e + 1], s2 = csrc[e + 2], s3 = csrc[e + 3];
    int s4 = csrc[e + 4], s5 = csrc[e + 5], s6 = csrc[e + 6], s7 = csrc[e + 7];
    float2 f0 = __half22float2(h2[(size_t)s0 * 64 + lane]);
    float2 f1 = __half22float2(h2[(size_t)s1 * 64 + lane]);
    float2 f2 = __half22float2(h2[(size_t)s2 * 64 + lane]);
    float2 f3 = __half22float2(h2[(size_t)s3 * 64 + lane]);
    float2 f4 = __half22float2(h2[(size_t)s4 * 64 + lane]);
    float2 f5 = __half22float2(h2[(size_t)s5 * 64 + lane]);
    float2 f6 = __half22float2(h2[(size_t)s6 * 64 + lane]);
    float2 f7 = __half22float2(h2[(size_t)s7 * 64 + lane]);
    if constexpr (PRE) {
      a0 += f0.x; a1 += f0.y;  b0_ += f1.x; b1_ += f1.y;
      c0 += f2.x; c1 += f2.y;  d0 += f3.x; d1 += f3.y;
      a0 += f4.x; a1 += f4.y;  b0_ += f5.x; b1_ += f5.y;
      c0 += f6.x; c1 += f6.y;  d0 += f7.x; d1 += f7.y;
    } else {
      float w0 = dinv[s0], w1 = dinv[s1], w2 = dinv[s2], w3 = dinv[s3];
      float w4 = dinv[s4], w5 = dinv[s5], w6 = dinv[s6], w7 = dinv[s7];
      a0 = fmaf(w0, f0.x, a0); a1 = fmaf(w0, f0.y, a1);
      b0_ = fmaf(w1, f1.x, b0_); b1_ = fmaf(w1, f1.y, b1_);
      c0 = fmaf(w2, f2.x, c0); c1 = fmaf(w2, f2.y, c1);
      d0 = fmaf(w3, f3.x, d0); d1 = fmaf(w3, f3.y, d1);
      a0 = fmaf(w4, f4.x, a0); a1 = fmaf(w4, f4.y, a1);
      b0_ = fmaf(w5, f5.x, b0_); b1_ = fmaf(w5, f5.y, b1_);
      c0 = fmaf(w6, f6.x, c0); c1 = fmaf(w6, f6.y, c1);
      d0 = fmaf(w7, f7.x, d0); d1 = fmaf(w7, f7.y, d1);
    }
  }
  if (e + 4 <= end) {
    int s0 = csrc[e + 0], s1 = csrc[e + 1], s2 = csrc[e + 2], s3 = csrc[e + 3];
    float2 f0 = __half22float2(h2[(size_t)s0 * 64 + lane]);
    float2 f1 = __half22float2(h2[(size_t)s1 * 64 + lane]);
    float2 f2 = __half22float2(h2[(size_t)s2 * 64 + lane]);
    float2 f3 = __half22float2(h2[(size_t)s3 * 64 + lane]);
    if constexpr (PRE) {
      a0 += f0.x; a1 += f0.y;  b0_ += f1.x; b1_ += f1.y;
      c0 += f2.x; c1 += f2.y;  d0 += f3.x; d1 += f3.y;
    } else {
      float w0 = dinv[s0], w1 = dinv[s1], w2 = dinv[s2], w3 = dinv[s3];
      a0 = fmaf(w0, f0.x, a0); a1 = fmaf(w0, f0.y, a1);
      b0_ = fmaf(w1, f1.x, b0_); b1_ = fmaf(w1, f1.y, b1_);
      c0 = fmaf(w2, f2.x, c0); c1 = fmaf(w2, f2.y, c1);
      d0 = fmaf(w3, f3.x, d0); d1 = fmaf(w3, f3.y, d1);
    }
    e += 4;
  }
  if (e + 2 <= end) {
    int s0 = csrc[e + 0], s1 = csrc[e + 1];
    float2 f0 = __half22float2(h2[(size_t)s0 * 64 + lane]);
    float2 f1 = __half22float2(h2[(size_t)s1 * 64 + lane]);
    if constexpr (PRE) {
      a0 += f0.x; a1 += f0.y;  b0_ += f1.x; b1_ += f1.y;
    } else {
      float w0 = dinv[s0], w1 = dinv[s1];
      a0 = fmaf(w0, f0.x, a0); a1 = fmaf(w0, f0.y, a1);
      b0_ = fmaf(w1, f1.x, b0_); b1_ = fmaf(w1, f1.y, b1_);
    }
    e += 2;
  }
  if (e < end) {
    int s0 = csrc[e];
    float2 f0 = __half22float2(h2[(size_t)s0 * 64 + lane]);
    if constexpr (PRE) {
      a0 += f0.x; a1 += f0.y;
    } else {
      float w0 = dinv[s0];
      a0 = fmaf(w0, f0.x, a0); a1 = fmaf(w0, f0.y, a1);
    }
  }

  float dv = dinv[node];
  float2 vs = __half22float2(h2[(size_t)node * 64 + lane]);
  float s0f, s1f;
  if constexpr (PRE) {
    // vs is already h' = dinv*H; self term dinv^2*H = dinv*h'
    s0f = ((a0 + b0_) + (c0 + d0) + vs.x) * dv;
    s1f = ((a1 + b1_) + (c1 + d1) + vs.y) * dv;
  } else {
    s0f = ((a0 + b0_) + (c0 + d0) + dv * vs.x) * dv;
    s1f = ((a1 + b1_) + (c1 + d1) + dv * vs.y) * dv;
  }

  float2 bb = ((const float2*)bias)[lane];
  float ox = elu1(s0f + bb.x);
  float oy = elu1(s1f + bb.y);
  ((__half2*)out)[(size_t)node * 64 + lane] = __floats2half2_rn(ox, oy);
}

// ---------- fused max-pool + linear head + softmax ----------
__global__ __launch_bounds__(256)
void pool_head(const __half* __restrict__ feat, const int* __restrict__ goff,
               const float* __restrict__ Wl, const float* __restrict__ bl,
               float* __restrict__ out) {
  int g = blockIdx.x;
  int t = threadIdx.x;          // 0..255
  int fp = t & 63;              // feature pair (2fp, 2fp+1)
  int r = t >> 6;               // row stream 0..3
  int beg = goff[g], end = goff[g + 1];
  const __half2* f2 = (const __half2*)feat;   // row stride 64

  float m0x = -INFINITY, m0y = -INFINITY, m1x = -INFINITY, m1y = -INFINITY;
  int i = beg + r;
  for (; i + 4 < end; i += 8) {
    float2 u = __half22float2(f2[(size_t)i * 64 + fp]);
    float2 v = __half22float2(f2[(size_t)(i + 4) * 64 + fp]);
    m0x = fmaxf(m0x, u.x); m0y = fmaxf(m0y, u.y);
    m1x = fmaxf(m1x, v.x); m1y = fmaxf(m1y, v.y);
  }
  for (; i < end; i += 4) {
    float2 u = __half22float2(f2[(size_t)i * 64 + fp]);
    m0x = fmaxf(m0x, u.x); m0y = fmaxf(m0y, u.y);
  }
  m0x = fmaxf(m0x, m1x); m0y = fmaxf(m0y, m1y);

  __shared__ float pl[4][HDIM];
  __shared__ float red[HDIM];
  __shared__ float lg[NCLS];
  pl[r][2 * fp] = m0x;
  pl[r][2 * fp + 1] = m0y;
  __syncthreads();

  if (t < HDIM) {
    float mm = fmaxf(fmaxf(pl[0][t], pl[1][t]), fmaxf(pl[2][t], pl[3][t]));
    if (beg == end) mm = 0.f;
    red[t] = mm;
  }
  __syncthreads();

  if (t < NCLS) {
    float acc = bl[t];
#pragma unroll
    for (int ff = 0; ff < HDIM; ++ff) acc = fmaf(red[ff], Wl[ff * NCLS + t], acc);
    lg[t] = acc;
  }
  __syncthreads();

  if (t < NCLS) {
    float mx = lg[0];
#pragma unroll
    for (int c = 1; c < NCLS; ++c) mx = fmaxf(mx, lg[c]);
    float ssum = 0.f;
#pragma unroll
    for (int c = 0; c < NCLS; ++c) ssum += __expf(lg[c] - mx);
    out[g * NCLS + t] = __expf(lg[t] - mx) / ssum;
  }
}

// ---------- launch ----------

extern "C" void kernel_launch(void* const* d_in, const int* in_sizes, int n_in,
                              void* d_out, int out_size, void* d_ws, size_t ws_size,
                              hipStream_t stream) {
  const float* x    = (const float*)d_in[0];
  const int*   ei   = (const int*)d_in[1];
  const int*   batch= (const int*)d_in[2];
  const float* W0 = (const float*)d_in[3]; const float* b0 = (const float*)d_in[4];
  const float* W1 = (const float*)d_in[5]; const float* b1 = (const float*)d_in[6];
  const float* W2 = (const float*)d_in[7]; const float* b2 = (const float*)d_in[8];
  const float* Wl = (const float*)d_in[9]; const float* bl = (const float*)d_in[10];
  float* out = (float*)d_out;

  char* w = (char*)d_ws;
  auto alloc = [&](size_t bytes) {
    char* p = w;
    w += (bytes + 255) & ~(size_t)255;
    return p;
  };
  int*    cbc    = (int*)   alloc((size_t)NCHUNKS * NB * 4);
  int*    cpre   = (int*)   alloc((size_t)NCHUNKS * NB * 4);
  int*    btot   = (int*)   alloc((size_t)NB * 4);
  int*    bbase  = (int*)   alloc((size_t)(NB + 1) * 4);
  int2*   ebuf   = (int2*)  alloc((size_t)N_EDGES * 8);
  int*    off    = (int*)   alloc((size_t)(N_NODES + 1) * 4);
  float*  dinv   = (float*) alloc((size_t)N_NODES * 4);
  int*    goff   = (int*)   alloc((size_t)(NGRAPH + 1) * 4);
  int*    csrc   = (int*)   alloc((size_t)N_EDGES * 4);
  half8*  Wswz   = (half8*) alloc((size_t)3 * 2048 * 16);
  __half* hbufA  = (__half*)alloc((size_t)N_NODES * HDIM * 2);
  __half* feat   = (__half*)alloc((size_t)N_NODES * HDIM * 2);

  // merged front-end: W swizzle || per-chunk bucket histogram || graph bounds
  front1<<<SWZ_BLOCKS + NCHUNKS + GB_BLOCKS, 256, 0, stream>>>(
      W0, W1, W2, Wswz, ei, cbc, batch, goff);

  // scan chain (dependent, tiny)
  scan_chunks<<<NB, 256, 0, stream>>>(cbc, cpre, btot);
  scan_base<<<1, 256, 0, stream>>>(btot, bbase);

  // scatter || gemm0 first half
  midA<<<NCHUNKS + GEMM_HALF, 256, 0, stream>>>(
      x, Wswz, hbufA, ei, cbc, cpre, bbase, ebuf);

  // csr finalize || gemm0 second half
  midB<<<NB + (GEMM_BLOCKS - GEMM_HALF), 256, 0, stream>>>(
      x, Wswz, hbufA, ebuf, bbase, off, dinv, csrc);

  const int AGG_BLOCKS = ((size_t)N_NODES * 64 + 255) / 256;   // 25000

  // layer 1: NONPRE (gemm0 ran before dinv existed)
  aggregate<false><<<AGG_BLOCKS, 256, 0, stream>>>(
      hbufA, off, csrc, dinv, b0, feat);

  // layers 2,3: GEMM epilogue prescales -> PRE aggregate (no dinv chain)
  gemm_mfma_h<<<GEMM_BLOCKS, 256, 0, stream>>>(feat, Wswz + 2048, hbufA,
                                               N_NODES, dinv);
  aggregate<true><<<AGG_BLOCKS, 256, 0, stream>>>(
      hbufA, off, csrc, dinv, b1, feat);

  gemm_mfma_h<<<GEMM_BLOCKS, 256, 0, stream>>>(feat, Wswz + 4096, hbufA,
                                               N_NODES, dinv);
  aggregate<true><<<AGG_BLOCKS, 256, 0, stream>>>(
      hbufA, off, csrc, dinv, b2, feat);

  pool_head<<<NGRAPH, 256, 0, stream>>>(feat, goff, Wl, bl, out);
}